// Round 13
// baseline (778.784 us; speedup 1.0000x reference)
//
#include <hip/hip_runtime.h>
#include <hip/hip_cooperative_groups.h>

namespace cg = cooperative_groups;

#define NN 131072   // nodes
#define NE 524288   // edges
#define NG 4096     // graphs

typedef __attribute__((ext_vector_type(8))) short bfx8;
typedef __attribute__((ext_vector_type(4))) float f32x4;

static __device__ __forceinline__ ushort f2bf(float f) {
    union { float f; unsigned u; } v; v.f = f;
    unsigned r = (v.u + 0x7fff + ((v.u >> 16) & 1)) >> 16;   // RNE
    return (ushort)r;
}
static __device__ __forceinline__ float bf2f(short s) {
    union { unsigned u; float f; } v;
    v.u = ((unsigned)(ushort)s) << 16;
    return v.f;
}

// ---------------- cooperative preprocessing: counts+prep / scan / fill ----------------
// s1: degree counts (atomics) + bf16 weight/x prep (independent work overlapped)
// s2: per-256-segment exclusive scan + dis      (blocks 0..511)
// s3: scan of 512 segment sums                  (block 0)
// s4: add segment offsets
// s5: CSR fill

#define PREP_TOTAL (NN * 96 + 78 * 96 + 156 * 96 + 312 * 160)

__global__ __launch_bounds__(256)
void k_preproc(const float* __restrict__ x, ushort* __restrict__ xb,
               const float* __restrict__ W1, ushort* __restrict__ W1T,
               const float* __restrict__ W2, ushort* __restrict__ W2T,
               const float* __restrict__ W3, ushort* __restrict__ W3T,
               const int* __restrict__ src, const int* __restrict__ dst,
               int* __restrict__ counts, int* __restrict__ rowstart,
               int* __restrict__ bsum, int* __restrict__ cursor,
               float* __restrict__ dis, int* __restrict__ col, float* __restrict__ wgt) {
    cg::grid_group grid = cg::this_grid();
    const int tid  = threadIdx.x;
    const int gidx = blockIdx.x * 256 + tid;
    const int gsz  = gridDim.x * 256;

    // ---- s1 ----
    for (int e = gidx; e < NE; e += gsz) atomicAdd(&counts[dst[e]], 1);
    for (int idx = gidx; idx < PREP_TOTAL; idx += gsz) {
        int t = idx;
        if (t < NN * 96) {
            int i = t / 96, c = t - i * 96;
            xb[t] = (c < 78) ? f2bf(x[i * 78 + c]) : (ushort)0;
            continue;
        }
        t -= NN * 96;
        if (t < 78 * 96) {                       // W1T [78][96], CI=78
            int n = t / 96, k = t - n * 96;
            W1T[t] = (k < 78) ? f2bf(W1[k * 78 + n]) : (ushort)0;
            continue;
        }
        t -= 78 * 96;
        if (t < 156 * 96) {                      // W2T [156][96], CI=78
            int n = t / 96, k = t - n * 96;
            W2T[t] = (k < 78) ? f2bf(W2[k * 156 + n]) : (ushort)0;
            continue;
        }
        t -= 156 * 96;
        {                                        // W3T [312][160], CI=156
            int n = t / 160, k = t - n * 160;
            W3T[t] = (k < 156) ? f2bf(W3[k * 312 + n]) : (ushort)0;
        }
    }
    grid.sync();

    // ---- s2 ----
    __shared__ int s[256];
    if (blockIdx.x < 512) {
        int i = blockIdx.x * 256 + tid;
        int v = counts[i];
        dis[i] = rsqrtf((float)(v + 1));          // +1 self-loop
        s[tid] = v;
        __syncthreads();
        for (int off = 1; off < 256; off <<= 1) {
            int xv = (tid >= off) ? s[tid - off] : 0;
            __syncthreads();
            s[tid] += xv;
            __syncthreads();
        }
        rowstart[i] = s[tid] - v;                 // exclusive within segment
        if (tid == 255) bsum[blockIdx.x] = s[tid];
    }
    grid.sync();

    // ---- s3 ----
    __shared__ int t2[512];
    if (blockIdx.x == 0) {
        int v1 = bsum[tid], v2 = bsum[tid + 256];
        t2[tid] = v1; t2[tid + 256] = v2;
        __syncthreads();
        for (int off = 1; off < 512; off <<= 1) {
            int a = (tid >= off) ? t2[tid - off] : 0;
            int b = (tid + 256 >= off) ? t2[tid + 256 - off] : 0;
            __syncthreads();
            t2[tid] += a;
            t2[tid + 256] += b;
            __syncthreads();
        }
        bsum[tid] = t2[tid] - v1;                 // exclusive
        bsum[tid + 256] = t2[tid + 256] - v2;
    }
    grid.sync();

    // ---- s4 ----
    for (int i = gidx; i < NN; i += gsz) rowstart[i] += bsum[i >> 8];
    if (gidx == 0) rowstart[NN] = NE;
    grid.sync();

    // ---- s5 ----
    for (int e = gidx; e < NE; e += gsz) {
        int sv = src[e], d = dst[e];
        int pos = rowstart[d] + atomicAdd(&cursor[d], 1);
        col[pos] = sv;
        wgt[pos] = dis[sv] * dis[d];
    }
}

// ---------------- fused layer: gather-agg into LDS, then MFMA GEMM (512 thr) -------
// Phase 1: 64 node-rows aggregated into XOR-swizzled sA; unit = (row, 16B chunk).
// Phase 2: 8 waves as 2x4 (32 rows x 16 cols per panel), B direct from L2, no barriers.

template<int KP, int LCH, int CO, int CPO, bool POOL>
__global__ __launch_bounds__(512)
void k_fused(const ushort* __restrict__ hin, const int* __restrict__ rowstart,
             const int* __restrict__ col, const float* __restrict__ wgt,
             const float* __restrict__ dis,
             const ushort* __restrict__ BT, const float* __restrict__ bias,
             const int* __restrict__ batch,
             ushort* __restrict__ hout, float* __restrict__ pooled) {
    constexpr int NCH = KP / 8;           // 16B chunks per row
    constexpr int LP  = LCH * 8;          // LDS row pitch in bf16 elems
    constexpr int NP  = (CO + 63) / 64;   // 64-col panels
    __shared__ ushort sA[64 * LP];

    const int tid  = threadIdx.x;
    const int row0 = blockIdx.x * 64;

    // ---- phase 1: gather-aggregate into sA ----
    for (int id = tid; id < 64 * NCH; id += 512) {
        int r  = id / NCH, kc = id - r * NCH;
        int i  = row0 + r;
        int ch = kc * 8;
        const ushort* gb = hin + ch;

        float d = dis[i];
        bfx8 self = *(const bfx8*)(hin + (size_t)i * KP + ch);
        float acc[8];
        #pragma unroll
        for (int k = 0; k < 8; ++k) acc[k] = d * d * bf2f(self[k]);

        int j = rowstart[i], j1 = rowstart[i + 1];
        for (; j + 4 <= j1; j += 4) {
            int c0 = col[j], c1 = col[j + 1], c2 = col[j + 2], c3 = col[j + 3];
            float w0 = wgt[j], w1 = wgt[j + 1], w2 = wgt[j + 2], w3 = wgt[j + 3];
            bfx8 g0 = *(const bfx8*)(gb + (size_t)c0 * KP);
            bfx8 g1 = *(const bfx8*)(gb + (size_t)c1 * KP);
            bfx8 g2 = *(const bfx8*)(gb + (size_t)c2 * KP);
            bfx8 g3 = *(const bfx8*)(gb + (size_t)c3 * KP);
            #pragma unroll
            for (int k = 0; k < 8; ++k) {
                acc[k] = fmaf(w0, bf2f(g0[k]), acc[k]);
                acc[k] = fmaf(w1, bf2f(g1[k]), acc[k]);
                acc[k] = fmaf(w2, bf2f(g2[k]), acc[k]);
                acc[k] = fmaf(w3, bf2f(g3[k]), acc[k]);
            }
        }
        for (; j < j1; ++j) {
            int c = col[j];
            float w = wgt[j];
            bfx8 g = *(const bfx8*)(gb + (size_t)c * KP);
            #pragma unroll
            for (int k = 0; k < 8; ++k) acc[k] = fmaf(w, bf2f(g[k]), acc[k]);
        }

        bfx8 ov;
        #pragma unroll
        for (int k = 0; k < 8; ++k) ov[k] = (short)f2bf(acc[k]);
        int swz = (kc & ~7) | ((kc & 7) ^ (r & 7));
        *(bfx8*)(sA + r * LP + swz * 8) = ov;
    }
    __syncthreads();

    // ---- phase 2: MFMA panel loop (8 waves: 2 row-groups x 4 col-groups) ----
    const int lane = tid & 63;
    const int wave = tid >> 6;            // 0..7
    const int wr = wave >> 2, wc = wave & 3;
    const int l15 = lane & 15, l4 = lane >> 4;
    const int r7 = l15 & 7;
    const int rowA0 = wr * 32 + l15;
    const int gbase = row0 + wr * 32;
    const int koff = l4 * 8;

    #pragma unroll
    for (int p = 0; p < NP; ++p) {
        const int bc0 = p * 64 + wc * 16 + l15;   // B row (output col)
        f32x4 acc[2] = {};
        #pragma unroll
        for (int ks = 0; ks < KP / 32; ++ks) {
            int chunk = l4 + ks * 4;
            int swz = (chunk & ~7) | ((chunk & 7) ^ r7);
            int off = swz * 8;
            bfx8 a0 = *(const bfx8*)(sA + rowA0 * LP + off);
            bfx8 a1 = *(const bfx8*)(sA + (rowA0 + 16) * LP + off);
            bfx8 b0 = {0,0,0,0,0,0,0,0};
            if (bc0 < CO) b0 = *(const bfx8*)(BT + (size_t)bc0 * KP + koff + ks * 32);
            acc[0] = __builtin_amdgcn_mfma_f32_16x16x32_bf16(a0, b0, acc[0], 0, 0, 0);
            acc[1] = __builtin_amdgcn_mfma_f32_16x16x32_bf16(a1, b0, acc[1], 0, 0, 0);
        }

        // epilogue. D-frag: row = fm*16 + (l>>4)*4 + j, col = l&15 (of 32x16 wave tile).
        const int cg = p * 64 + wc * 16 + l15;
        if constexpr (POOL) {
            const bool uni = (batch[gbase] == batch[gbase + 31]);
            bool cok = cg < CO;
            float bs = cok ? bias[cg] : 0.0f;
            if (uni) {
                float m = -1e30f;
                #pragma unroll
                for (int fm = 0; fm < 2; ++fm)
                    #pragma unroll
                    for (int j = 0; j < 4; ++j)
                        m = fmaxf(m, acc[fm][j]);
                m = fmaxf(m, __shfl_xor(m, 16));
                m = fmaxf(m, __shfl_xor(m, 32));
                if (l4 == 0 && cok) {
                    int g = batch[gbase];
                    float v = fmaxf(m + bs, 0.0f);
                    atomicMax((int*)&pooled[g * CO + cg], __float_as_int(v));
                }
            } else {
                #pragma unroll
                for (int fm = 0; fm < 2; ++fm)
                    #pragma unroll
                    for (int j = 0; j < 4; ++j) {
                        if (cok) {
                            int rg = gbase + fm * 16 + l4 * 4 + j;
                            int g = batch[rg];
                            float v = fmaxf(acc[fm][j] + bs, 0.0f);
                            atomicMax((int*)&pooled[g * CO + cg], __float_as_int(v));
                        }
                    }
            }
        } else {
            if (cg < CPO) {
                float bs = (cg < CO) ? bias[cg] : 0.0f;
                #pragma unroll
                for (int fm = 0; fm < 2; ++fm)
                    #pragma unroll
                    for (int j = 0; j < 4; ++j) {
                        int row = gbase + fm * 16 + l4 * 4 + j;
                        float v = (cg < CO) ? fmaxf(acc[fm][j] + bs, 0.0f) : 0.0f;
                        hout[(size_t)row * CPO + cg] = f2bf(v);
                    }
            }
        }
    }
}

// ---------------- final FC: out[g][c] = fcb[c] + dot(pooled[g,:], fcW[:,c]) ----------

__global__ __launch_bounds__(256)
void k_fc(const float* __restrict__ pooled, const float* __restrict__ fcW,
          const float* __restrict__ fcb, float* __restrict__ out) {
    __shared__ float sp[8][312];
    const int tid = threadIdx.x;
    const int g0 = blockIdx.x * 8;

    for (int k = tid; k < 8 * 312; k += 256)
        ((float*)sp)[k] = pooled[(size_t)g0 * 312 + k];
    __syncthreads();

    const int half = tid >> 7;       // 0..1 -> graphs g0+half*4 .. +3
    const int c = tid & 127;
    float b = fcb[c];
    float acc0 = b, acc1 = b, acc2 = b, acc3 = b;
    const float* wp = fcW + c;
    const float* p0 = sp[half * 4 + 0];
    const float* p1 = sp[half * 4 + 1];
    const float* p2 = sp[half * 4 + 2];
    const float* p3 = sp[half * 4 + 3];
    #pragma unroll 4
    for (int k = 0; k < 312; ++k) {
        float w = wp[(size_t)k * 128];
        acc0 = fmaf(p0[k], w, acc0);
        acc1 = fmaf(p1[k], w, acc1);
        acc2 = fmaf(p2[k], w, acc2);
        acc3 = fmaf(p3[k], w, acc3);
    }
    float* o = out + (size_t)(g0 + half * 4) * 128 + c;
    o[0] = acc0; o[128] = acc1; o[256] = acc2; o[384] = acc3;
}

// ---------------- launch ----------------

extern "C" void kernel_launch(void* const* d_in, const int* in_sizes, int n_in,
                              void* d_out, int out_size, void* d_ws, size_t ws_size,
                              hipStream_t stream) {
    const float* x    = (const float*)d_in[0];
    const int*   ei   = (const int*)d_in[1];
    const int*   srcv = ei;
    const int*   dstv = ei + NE;
    const int*   batch = (const int*)d_in[2];
    const float* W1 = (const float*)d_in[3];
    const float* b1 = (const float*)d_in[4];
    const float* W2 = (const float*)d_in[5];
    const float* b2 = (const float*)d_in[6];
    const float* W3 = (const float*)d_in[7];
    const float* b3 = (const float*)d_in[8];
    const float* fcW = (const float*)d_in[9];
    const float* fcb = (const float*)d_in[10];
    float* out = (float*)d_out;

    char* ws = (char*)d_ws;
    size_t off = 0;
    auto take = [&](size_t bytes) -> void* {
        void* p = ws + off;
        off += (bytes + 255) & ~(size_t)255;
        return p;
    };
    // counts/cursor/pooled contiguous -> one memset
    int*    counts   = (int*)take((size_t)NN * 4);
    int*    cursor   = (int*)take((size_t)NN * 4);
    float*  pooled   = (float*)take((size_t)NG * 312 * 4);
    int*    rowstart = (int*)take((size_t)(NN + 1) * 4);
    float*  dis      = (float*)take((size_t)NN * 4);
    int*    bsum     = (int*)take(512 * 4);
    int*    col      = (int*)take((size_t)NE * 4);
    float*  wgt      = (float*)take((size_t)NE * 4);
    ushort* xb       = (ushort*)take((size_t)NN * 96 * 2);
    ushort* h1       = (ushort*)take((size_t)NN * 96 * 2);
    ushort* h2       = (ushort*)take((size_t)NN * 160 * 2);
    ushort* W1T      = (ushort*)take((size_t)78 * 96 * 2);
    ushort* W2T      = (ushort*)take((size_t)156 * 96 * 2);
    ushort* W3T      = (ushort*)take((size_t)312 * 160 * 2);

    hipMemsetAsync(counts, 0, (size_t)NN * 4 + (size_t)NN * 4 + (size_t)NG * 312 * 4, stream);

    // cooperative preprocessing: counts+prep / scan / fill in ONE dispatch
    {
        void* args[] = {
            (void*)&x, (void*)&xb,
            (void*)&W1, (void*)&W1T, (void*)&W2, (void*)&W2T, (void*)&W3, (void*)&W3T,
            (void*)&srcv, (void*)&dstv,
            (void*)&counts, (void*)&rowstart, (void*)&bsum, (void*)&cursor,
            (void*)&dis, (void*)&col, (void*)&wgt
        };
        hipLaunchCooperativeKernel((const void*)k_preproc, dim3(1024), dim3(256),
                                   args, 0, stream);
    }

    // fused layers: gather-agg (phase 1) + MFMA GEMM (phase 2), 512 threads
    k_fused<96, 16, 78, 96, false><<<NN / 64, 512, 0, stream>>>(
        xb, rowstart, col, wgt, dis, W1T, b1, nullptr, h1, nullptr);
    k_fused<96, 16, 156, 160, false><<<NN / 64, 512, 0, stream>>>(
        h1, rowstart, col, wgt, dis, W2T, b2, nullptr, h2, nullptr);
    k_fused<160, 24, 312, 312, true><<<NN / 64, 512, 0, stream>>>(
        h2, rowstart, col, wgt, dis, W3T, b3, batch, nullptr, pooled);

    // FC (fp32, 8 graphs/block, 512 blocks)
    k_fc<<<NG / 8, 256, 0, stream>>>(pooled, fcW, fcb, out);
}